// Round 13
// baseline (646.915 us; speedup 1.0000x reference)
//
#include <hip/hip_runtime.h>
#include <stdint.h>

typedef float f32x4 __attribute__((ext_vector_type(4)));

// Phase 1 (line-granularity scan — information floor for adaptive probing):
//   Each 256-float chunk is ONE-HOT; the 1.0 lives in exactly one of the
//   chunk's 8 128-B lines. Scan lines sequentially with early exit: probe =
//   one ushort per lane (64 ushorts = 1 line); hot float 1.0f has high half
//   0x3F80, zeros are 0x0000, so ballot(val==0x3F80) locates it.
//   Expected reads: 4.5 lines = 576 B/chunk (vs 768 B for R12's half-skip,
//   1024 B full) -> phase-1 demand 537 -> ~302 MB. Probe branches are
//   wave-uniform; each round issues ALL unfound chunks' probes before
//   resolving (8-way MLP per round). Dependent depth ~8 — proven free
//   (R9/R11 null, R12's conditional read cost nothing; we are byte-rate
//   capped at ~4.8 TB/s NT-read, not latency capped).
// Phase 2: 4 B wave-uniform read (L2-hot) -> 4 KiB one-hot cached stores;
//   pure write stream, fill-kernel pattern (6.55 TB/s reference).

__global__ __launch_bounds__(256) void vm_phase1(
    const float* __restrict__ a_bytes,
    const float* __restrict__ b_bytes,
    uint32_t* __restrict__ ws,
    int n_words)
{
    const int lane = threadIdx.x & 63;
    const int w    = blockIdx.x * 4 + (threadIdx.x >> 6);
    if (w >= n_words) return;

    const unsigned short* pa = (const unsigned short*)(a_bytes + (long)w * 1024);
    const unsigned short* pb = (const unsigned short*)(b_bytes + (long)w * 1024);
    // chunk c (<4: a chunk c, >=4: b chunk c-4) starts at ushort offset 512*c'.
    // line r of a chunk: ushort offset r*64 + lane.

    unsigned short val[8];
    uint32_t idx[8];
    bool found[8];

    // ---- round 0: probe line 0 of every chunk (8 independent 128-B loads) ----
#pragma unroll
    for (int c = 0; c < 8; ++c) {
        const unsigned short* p =
            (c < 4 ? pa + c * 512 : pb + (c - 4) * 512) + lane;
        val[c] = __builtin_nontemporal_load(p);
    }
#pragma unroll
    for (int c = 0; c < 8; ++c) {
        const uint64_t m = __ballot(val[c] == (unsigned short)0x3F80);
        found[c] = (m != 0);
        idx[c] = (((uint32_t)__ffsll((unsigned long long)m)) - 1u) >> 1;
    }

    // ---- rounds 1..7: probe next line of each unfound chunk ----
    for (int r = 1; r < 8; ++r) {
        bool all = found[0] & found[1] & found[2] & found[3] &
                   found[4] & found[5] & found[6] & found[7];
        if (all) break;                               // wave-uniform
#pragma unroll
        for (int c = 0; c < 8; ++c) {
            if (!found[c]) {                          // wave-uniform
                const unsigned short* p =
                    (c < 4 ? pa + c * 512 : pb + (c - 4) * 512) + r * 64 + lane;
                val[c] = __builtin_nontemporal_load(p);
            }
        }
#pragma unroll
        for (int c = 0; c < 8; ++c) {
            if (!found[c]) {
                const uint64_t m = __ballot(val[c] == (unsigned short)0x3F80);
                if (m != 0) {
                    found[c] = true;
                    idx[c] = (uint32_t)r * 32u +
                             ((((uint32_t)__ffsll((unsigned long long)m)) - 1u) >> 1);
                }
            }
        }
    }

    const uint32_t aw = idx[0] | (idx[1] << 8) | (idx[2] << 16) | (idx[3] << 24);
    const uint32_t bw = idx[4] | (idx[5] << 8) | (idx[6] << 16) | (idx[7] << 24);
    const uint32_t s = aw + bw;   // ripple-carry add; carry out of byte 3 dropped
    const uint32_t o = s ^ aw;    // chained per-byte XOR with operand a
    if (lane == 0) ws[w] = o;
}

__global__ __launch_bounds__(256) void vm_phase2(
    const uint32_t* __restrict__ ws,
    float* __restrict__ out,
    int n_words)
{
    const int lane = threadIdx.x & 63;
    const int w    = blockIdx.x * 4 + (threadIdx.x >> 6);
    if (w >= n_words) return;

    const uint32_t o = ws[w];            // wave-uniform -> scalar load, L2-hot
    float* po = out + (long)w * 1024 + lane * 4;
    const int j = lane * 4;
#pragma unroll
    for (int k = 0; k < 4; ++k) {
        const int oi = (int)((o >> (8 * k)) & 255u);
        f32x4 ov;
        ov.x = (j     == oi) ? 1.0f : 0.0f;
        ov.y = (j + 1 == oi) ? 1.0f : 0.0f;
        ov.z = (j + 2 == oi) ? 1.0f : 0.0f;
        ov.w = (j + 3 == oi) ? 1.0f : 0.0f;
        *(f32x4*)(po + k * 256) = ov;    // cached store, fill-kernel pattern
    }
}

// Fallback: fused all-NT single pass (R5) if ws is unavailable/too small.
__device__ __forceinline__ uint32_t idx_of16(const f32x4 v) {
    const uint64_t m0 = __ballot(v.x > 0.5f);
    const uint64_t m1 = __ballot(v.y > 0.5f);
    const uint64_t m2 = __ballot(v.z > 0.5f);
    const uint64_t m3 = __ballot(v.w > 0.5f);
    const uint64_t m  = m0 | m1 | m2 | m3;
    const uint32_t hl = (uint32_t)__ffsll((unsigned long long)m) - 1u;
    const uint32_t c  = (m1 ? 1u : 0u) | (m2 ? 2u : 0u) | (m3 ? 3u : 0u);
    return hl * 4u + c;
}

__global__ __launch_bounds__(256) void vm_fused(
    const float* __restrict__ a_bytes,
    const float* __restrict__ b_bytes,
    float* __restrict__ out,
    int n_words)
{
    const int lane = threadIdx.x & 63;
    const int w    = blockIdx.x * 4 + (threadIdx.x >> 6);
    if (w >= n_words) return;

    const long base = (long)w * 1024 + lane * 4;
    const float* pa = a_bytes + base;
    const float* pb = b_bytes + base;

    const f32x4 a0 = __builtin_nontemporal_load((const f32x4*)(pa));
    const f32x4 a1 = __builtin_nontemporal_load((const f32x4*)(pa + 256));
    const f32x4 a2 = __builtin_nontemporal_load((const f32x4*)(pa + 512));
    const f32x4 a3 = __builtin_nontemporal_load((const f32x4*)(pa + 768));
    const f32x4 b0 = __builtin_nontemporal_load((const f32x4*)(pb));
    const f32x4 b1 = __builtin_nontemporal_load((const f32x4*)(pb + 256));
    const f32x4 b2 = __builtin_nontemporal_load((const f32x4*)(pb + 512));
    const f32x4 b3 = __builtin_nontemporal_load((const f32x4*)(pb + 768));

    const uint32_t aw = idx_of16(a0) | (idx_of16(a1) << 8) |
                        (idx_of16(a2) << 16) | (idx_of16(a3) << 24);
    const uint32_t bw = idx_of16(b0) | (idx_of16(b1) << 8) |
                        (idx_of16(b2) << 16) | (idx_of16(b3) << 24);
    const uint32_t s = aw + bw;
    const uint32_t o = s ^ aw;

    float* po = out + base;
    const int j = lane * 4;
#pragma unroll
    for (int k = 0; k < 4; ++k) {
        const int oi = (int)((o >> (8 * k)) & 255u);
        f32x4 ov;
        ov.x = (j     == oi) ? 1.0f : 0.0f;
        ov.y = (j + 1 == oi) ? 1.0f : 0.0f;
        ov.z = (j + 2 == oi) ? 1.0f : 0.0f;
        ov.w = (j + 3 == oi) ? 1.0f : 0.0f;
        __builtin_nontemporal_store(ov, (f32x4*)(po + k * 256));
    }
}

extern "C" void kernel_launch(void* const* d_in, const int* in_sizes, int n_in,
                              void* d_out, int out_size, void* d_ws, size_t ws_size,
                              hipStream_t stream)
{
    const float* a_bytes = (const float*)d_in[0];  // [B,4,256]
    const float* b_bytes = (const float*)d_in[1];  // [B,4,256]
    float* out = (float*)d_out;                    // [B,4,256]
    const int n_words = in_sizes[0] / 1024;        // B
    const int blocks  = (n_words + 3) / 4;         // 4 waves/block, 1 word/wave

    if (d_ws != nullptr && ws_size >= (size_t)n_words * 4) {
        uint32_t* ws = (uint32_t*)d_ws;
        vm_phase1<<<blocks, 256, 0, stream>>>(a_bytes, b_bytes, ws, n_words);
        vm_phase2<<<blocks, 256, 0, stream>>>(ws, out, n_words);
    } else {
        vm_fused<<<blocks, 256, 0, stream>>>(a_bytes, b_bytes, out, n_words);
    }
}

// Round 14
// 547.816 us; speedup vs baseline: 1.1809x; 1.1809x over previous
//
#include <hip/hip_runtime.h>
#include <stdint.h>

typedef float f32x4 __attribute__((ext_vector_type(4)));
typedef float f32x2 __attribute__((ext_vector_type(2)));

// Phase 1 (half-skip with 16B/lane PAIRED requests):
//   R12's scheme (read first half of each one-hot chunk; read second half only
//   on miss, p=1/2) but with requests reshaped: lanes 0-31 carry chunk 2p's
//   first half, lanes 32-63 carry chunk 2p+1's -> one 1024-B f32x4 request
//   per CHUNK PAIR. Rate ledger (R5/R8/R12/R13): effective NT-read rate is
//   monotone in per-lane width (16B: 4.7-4.85 TB/s, 8B: ~4.1, 2B: ~1.5), so
//   same expected bytes (~404 MB) in 16B/lane shape should run at ~4.7.
//   Round 2: both-missed pair -> paired f32x4; single-missed -> f32x2.
//   All branches wave-uniform; issue-all-then-resolve (R12-proven).
// Phase 2: 4 B wave-uniform read (L2-hot) -> 4 KiB one-hot cached stores;
//   pure write stream, fill-kernel pattern (6.55 TB/s reference).

__global__ __launch_bounds__(256) void vm_phase1(
    const float* __restrict__ a_bytes,
    const float* __restrict__ b_bytes,
    uint32_t* __restrict__ ws,
    int n_words)
{
    const int lane = threadIdx.x & 63;
    const int w    = blockIdx.x * 4 + (threadIdx.x >> 6);
    if (w >= n_words) return;

    // pair p: p<2 -> a chunks {2p,2p+1}; p>=2 -> b chunks {2(p-2),2(p-2)+1}
    const float* pa = a_bytes + (long)w * 1024;
    const float* pb = b_bytes + (long)w * 1024;
    const float* pair_base[4] = { pa, pa + 512, pb, pb + 512 };

    // float offset inside a pair for FIRST halves:
    // lanes 0-31 -> chunk0 floats [0,128); lanes 32-63 -> chunk1 floats [256,384)
    const int sub = (lane & 31) * 4 + (lane >> 5) * 256;

    // ---- round 1: 4 paired f32x4 NT loads (1024 B each) ----
    f32x4 v[4];
#pragma unroll
    for (int p = 0; p < 4; ++p)
        v[p] = __builtin_nontemporal_load((const f32x4*)(pair_base[p] + sub));

    uint32_t idx[8];
    bool found[8];
#pragma unroll
    for (int p = 0; p < 4; ++p) {
        const uint64_t m0 = __ballot(v[p].x > 0.5f);
        const uint64_t m1 = __ballot(v[p].y > 0.5f);
        const uint64_t m2 = __ballot(v[p].z > 0.5f);
        const uint64_t m3 = __ballot(v[p].w > 0.5f);
        const uint64_t ma = m0 | m1 | m2 | m3;
        // low half-wave -> chunk 2p
        const uint32_t mlo = (uint32_t)ma;
        found[2 * p] = (mlo != 0);
        {
            const uint32_t l = (uint32_t)__ffs(mlo) - 1u;
            const uint32_t c = (((uint32_t)(m1 >> l)) & 1u) * 1u +
                               (((uint32_t)(m2 >> l)) & 1u) * 2u +
                               (((uint32_t)(m3 >> l)) & 1u) * 3u;
            idx[2 * p] = 4u * l + c;
        }
        // high half-wave -> chunk 2p+1
        const uint32_t mhi = (uint32_t)(ma >> 32);
        found[2 * p + 1] = (mhi != 0);
        {
            const uint32_t l = (uint32_t)__ffs(mhi) - 1u;
            const uint32_t c = (((uint32_t)(m1 >> (l + 32))) & 1u) * 1u +
                               (((uint32_t)(m2 >> (l + 32))) & 1u) * 2u +
                               (((uint32_t)(m3 >> (l + 32))) & 1u) * 3u;
            idx[2 * p + 1] = 4u * l + c;
        }
    }

    // ---- round 2 issue (all loads before any resolve; wave-uniform branches):
    //   both missed  -> paired f32x4 of both second halves (1024 B)
    //   one missed   -> f32x2 over the missed chunk's second half (512 B)
    f32x4 v2[4];
#pragma unroll
    for (int p = 0; p < 4; ++p) {
        const bool f0 = found[2 * p], f1 = found[2 * p + 1];
        if (!f0 && !f1) {
            v2[p] = __builtin_nontemporal_load(
                (const f32x4*)(pair_base[p] + 128 + sub));
        } else if (!f0) {
            const f32x2 t = __builtin_nontemporal_load(
                (const f32x2*)(pair_base[p] + 128 + lane * 2));
            v2[p].x = t.x; v2[p].y = t.y;
        } else if (!f1) {
            const f32x2 t = __builtin_nontemporal_load(
                (const f32x2*)(pair_base[p] + 384 + lane * 2));
            v2[p].x = t.x; v2[p].y = t.y;
        }
    }

    // ---- round 2 resolve ----
#pragma unroll
    for (int p = 0; p < 4; ++p) {
        const bool f0 = found[2 * p], f1 = found[2 * p + 1];
        if (!f0 && !f1) {
            const uint64_t m0 = __ballot(v2[p].x > 0.5f);
            const uint64_t m1 = __ballot(v2[p].y > 0.5f);
            const uint64_t m2 = __ballot(v2[p].z > 0.5f);
            const uint64_t m3 = __ballot(v2[p].w > 0.5f);
            const uint64_t ma = m0 | m1 | m2 | m3;
            const uint32_t mlo = (uint32_t)ma;
            {
                const uint32_t l = (uint32_t)__ffs(mlo) - 1u;
                const uint32_t c = (((uint32_t)(m1 >> l)) & 1u) * 1u +
                                   (((uint32_t)(m2 >> l)) & 1u) * 2u +
                                   (((uint32_t)(m3 >> l)) & 1u) * 3u;
                idx[2 * p] = 128u + 4u * l + c;
            }
            const uint32_t mhi = (uint32_t)(ma >> 32);
            {
                const uint32_t l = (uint32_t)__ffs(mhi) - 1u;
                const uint32_t c = (((uint32_t)(m1 >> (l + 32))) & 1u) * 1u +
                                   (((uint32_t)(m2 >> (l + 32))) & 1u) * 2u +
                                   (((uint32_t)(m3 >> (l + 32))) & 1u) * 3u;
                idx[2 * p + 1] = 128u + 4u * l + c;
            }
        } else if (!f0 || !f1) {
            const uint64_t m0 = __ballot(v2[p].x > 0.5f);
            const uint64_t m1 = __ballot(v2[p].y > 0.5f);
            const uint64_t m  = m0 | m1;
            const uint32_t l  = (uint32_t)__ffsll((unsigned long long)m) - 1u;
            const uint32_t c  = (uint32_t)((m1 >> l) & 1u);
            idx[!f0 ? 2 * p : 2 * p + 1] = 128u + 2u * l + c;
        }
    }

    const uint32_t aw = idx[0] | (idx[1] << 8) | (idx[2] << 16) | (idx[3] << 24);
    const uint32_t bw = idx[4] | (idx[5] << 8) | (idx[6] << 16) | (idx[7] << 24);
    const uint32_t s = aw + bw;   // ripple-carry add; carry out of byte 3 dropped
    const uint32_t o = s ^ aw;    // chained per-byte XOR with operand a
    if (lane == 0) ws[w] = o;
}

__global__ __launch_bounds__(256) void vm_phase2(
    const uint32_t* __restrict__ ws,
    float* __restrict__ out,
    int n_words)
{
    const int lane = threadIdx.x & 63;
    const int w    = blockIdx.x * 4 + (threadIdx.x >> 6);
    if (w >= n_words) return;

    const uint32_t o = ws[w];            // wave-uniform -> scalar load, L2-hot
    float* po = out + (long)w * 1024 + lane * 4;
    const int j = lane * 4;
#pragma unroll
    for (int k = 0; k < 4; ++k) {
        const int oi = (int)((o >> (8 * k)) & 255u);
        f32x4 ov;
        ov.x = (j     == oi) ? 1.0f : 0.0f;
        ov.y = (j + 1 == oi) ? 1.0f : 0.0f;
        ov.z = (j + 2 == oi) ? 1.0f : 0.0f;
        ov.w = (j + 3 == oi) ? 1.0f : 0.0f;
        *(f32x4*)(po + k * 256) = ov;    // cached store, fill-kernel pattern
    }
}

// Fallback: fused all-NT single pass (R5) if ws is unavailable/too small.
__device__ __forceinline__ uint32_t idx_of16(const f32x4 v) {
    const uint64_t m0 = __ballot(v.x > 0.5f);
    const uint64_t m1 = __ballot(v.y > 0.5f);
    const uint64_t m2 = __ballot(v.z > 0.5f);
    const uint64_t m3 = __ballot(v.w > 0.5f);
    const uint64_t m  = m0 | m1 | m2 | m3;
    const uint32_t hl = (uint32_t)__ffsll((unsigned long long)m) - 1u;
    const uint32_t c  = (m1 ? 1u : 0u) | (m2 ? 2u : 0u) | (m3 ? 3u : 0u);
    return hl * 4u + c;
}

__global__ __launch_bounds__(256) void vm_fused(
    const float* __restrict__ a_bytes,
    const float* __restrict__ b_bytes,
    float* __restrict__ out,
    int n_words)
{
    const int lane = threadIdx.x & 63;
    const int w    = blockIdx.x * 4 + (threadIdx.x >> 6);
    if (w >= n_words) return;

    const long base = (long)w * 1024 + lane * 4;
    const float* pa = a_bytes + base;
    const float* pb = b_bytes + base;

    const f32x4 a0 = __builtin_nontemporal_load((const f32x4*)(pa));
    const f32x4 a1 = __builtin_nontemporal_load((const f32x4*)(pa + 256));
    const f32x4 a2 = __builtin_nontemporal_load((const f32x4*)(pa + 512));
    const f32x4 a3 = __builtin_nontemporal_load((const f32x4*)(pa + 768));
    const f32x4 b0 = __builtin_nontemporal_load((const f32x4*)(pb));
    const f32x4 b1 = __builtin_nontemporal_load((const f32x4*)(pb + 256));
    const f32x4 b2 = __builtin_nontemporal_load((const f32x4*)(pb + 512));
    const f32x4 b3 = __builtin_nontemporal_load((const f32x4*)(pb + 768));

    const uint32_t aw = idx_of16(a0) | (idx_of16(a1) << 8) |
                        (idx_of16(a2) << 16) | (idx_of16(a3) << 24);
    const uint32_t bw = idx_of16(b0) | (idx_of16(b1) << 8) |
                        (idx_of16(b2) << 16) | (idx_of16(b3) << 24);
    const uint32_t s = aw + bw;
    const uint32_t o = s ^ aw;

    float* po = out + base;
    const int j = lane * 4;
#pragma unroll
    for (int k = 0; k < 4; ++k) {
        const int oi = (int)((o >> (8 * k)) & 255u);
        f32x4 ov;
        ov.x = (j     == oi) ? 1.0f : 0.0f;
        ov.y = (j + 1 == oi) ? 1.0f : 0.0f;
        ov.z = (j + 2 == oi) ? 1.0f : 0.0f;
        ov.w = (j + 3 == oi) ? 1.0f : 0.0f;
        __builtin_nontemporal_store(ov, (f32x4*)(po + k * 256));
    }
}

extern "C" void kernel_launch(void* const* d_in, const int* in_sizes, int n_in,
                              void* d_out, int out_size, void* d_ws, size_t ws_size,
                              hipStream_t stream)
{
    const float* a_bytes = (const float*)d_in[0];  // [B,4,256]
    const float* b_bytes = (const float*)d_in[1];  // [B,4,256]
    float* out = (float*)d_out;                    // [B,4,256]
    const int n_words = in_sizes[0] / 1024;        // B
    const int blocks  = (n_words + 3) / 4;         // 4 waves/block, 1 word/wave

    if (d_ws != nullptr && ws_size >= (size_t)n_words * 4) {
        uint32_t* ws = (uint32_t*)d_ws;
        vm_phase1<<<blocks, 256, 0, stream>>>(a_bytes, b_bytes, ws, n_words);
        vm_phase2<<<blocks, 256, 0, stream>>>(ws, out, n_words);
    } else {
        vm_fused<<<blocks, 256, 0, stream>>>(a_bytes, b_bytes, out, n_words);
    }
}